// Round 1
// baseline (341.982 us; speedup 1.0000x reference)
//
#include <hip/hip_runtime.h>

#define NN 19        // nodes
#define NT 4096
#define LAT 512
#define HID 2048
#define NE 342       // edges
#define ATS 32       // transposed-activation row stride (floats), 128B aligned

// ---------- edge dtype detection (int64 stored as pairs vs int32) ----------
__device__ __forceinline__ bool edges_are_i64(const int* __restrict__ e) {
    // If the buffer really holds int64 values (all in [0,19)), every odd
    // int32 word is a zero high-word. For genuine int32 data, odd words are
    // random values in [0,19): P(all 171 are zero) ~ (1/19)^171 ~ 0.
    int acc = 0;
    for (int i = 1; i < NE; i += 2) acc |= e[i];
    return acc == 0;
}
__device__ __forceinline__ int edge_src(const int* e, bool i64, int idx) {
    return i64 ? e[2 * idx] : e[idx];
}
__device__ __forceinline__ int edge_dst(const int* e, bool i64, int idx) {
    return i64 ? e[2 * NE + 2 * idx] : e[NE + idx];
}

// ---------- agg1: h0 = z + segment_sum(z[src] -> dst), write transposed ----------
__global__ __launch_bounds__(512) void agg1_kernel(const float* __restrict__ z,
                                                   const int* __restrict__ eidx,
                                                   float* __restrict__ h0t) {
    __shared__ float h[NN * LAT];
    const int t = threadIdx.x;  // 512 threads, one per feature dim
    const bool i64 = edges_are_i64(eidx);
#pragma unroll
    for (int i = 0; i < NN; ++i) h[i * LAT + t] = z[i * LAT + t];
    for (int e = 0; e < NE; ++e) {
        const int s = edge_src(eidx, i64, e);
        const int d = edge_dst(eidx, i64, e);
        h[d * LAT + t] += z[s * LAT + t];  // each thread owns column t: no race
    }
#pragma unroll
    for (int i = 0; i < NN; ++i) h0t[t * ATS + i] = h[i * LAT + t];
}

// ---------- agg2: h2 = h1 + segment_sum(h1[src] -> dst), transposed in/out ----------
__global__ __launch_bounds__(256) void agg2_kernel(const float* __restrict__ h1t,
                                                   const int* __restrict__ eidx,
                                                   float* __restrict__ h2t) {
    __shared__ float cur[NN][256];
    __shared__ float orig[NN][256];
    const int t = threadIdx.x;
    const int k = blockIdx.x * 256 + t;  // feature dim (0..2047)
    const bool i64 = edges_are_i64(eidx);
#pragma unroll
    for (int i = 0; i < NN; ++i) {
        const float v = h1t[k * ATS + i];
        cur[i][t] = v;
        orig[i][t] = v;
    }
    for (int e = 0; e < NE; ++e) {
        const int s = edge_src(eidx, i64, e);
        const int d = edge_dst(eidx, i64, e);
        cur[d][t] += orig[s][t];  // per-thread column: no race
    }
#pragma unroll
    for (int i = 0; i < NN; ++i) h2t[k * ATS + i] = cur[i][t];
}

// ---------- skinny GEMM partial: part[chunk][19][N] += At[19,K-chunk] @ W[K-chunk,N] ----------
// At is transposed [K][ATS]; reads of At are wave-uniform -> scalar loads.
__global__ __launch_bounds__(256) void gemm19_partial(const float* __restrict__ At,
                                                      const float* __restrict__ W,
                                                      float* __restrict__ part,
                                                      int N, int BK) {
    const int n = blockIdx.x * 256 + threadIdx.x;
    const int k0 = blockIdx.y * BK;
    float acc[NN];
#pragma unroll
    for (int i = 0; i < NN; ++i) acc[i] = 0.f;
    const float* __restrict__ a = At + (size_t)k0 * ATS;
    const float* __restrict__ w = W + (size_t)k0 * N + n;
#pragma unroll 4
    for (int k = 0; k < BK; ++k) {
        const float wv = w[(size_t)k * N];
#pragma unroll
        for (int i = 0; i < NN; ++i)
            acc[i] = fmaf(a[k * ATS + i], wv, acc[i]);
    }
    float* __restrict__ p = part + (size_t)(blockIdx.y * NN) * N + n;
#pragma unroll
    for (int i = 0; i < NN; ++i) p[(size_t)i * N] = acc[i];
}

// ---------- reduce partials + bias + relu, write transposed for next stage ----------
__global__ __launch_bounds__(256) void gemm19_reduce_relu_t(const float* __restrict__ part,
                                                            const float* __restrict__ bias,
                                                            float* __restrict__ outT,
                                                            int N, int nchunk) {
    const int n = blockIdx.x * 256 + threadIdx.x;
    const float b = bias[n];
    float s[NN];
#pragma unroll
    for (int i = 0; i < NN; ++i) s[i] = b;
    for (int c = 0; c < nchunk; ++c) {
        const float* __restrict__ p = part + (size_t)(c * NN) * N + n;
#pragma unroll
        for (int i = 0; i < NN; ++i) s[i] += p[(size_t)i * N];
    }
#pragma unroll
    for (int i = 0; i < NN; ++i) outT[n * ATS + i] = s[i] > 0.f ? s[i] : 0.f;
}

// ---------- reduce partials + bias (no relu), write row-major [19][N] to output ----------
__global__ __launch_bounds__(256) void gemm19_reduce_out(const float* __restrict__ part,
                                                         const float* __restrict__ bias,
                                                         float* __restrict__ out,
                                                         int N, int nchunk) {
    const int n = blockIdx.x * 256 + threadIdx.x;
    const float b = bias[n];
#pragma unroll
    for (int i = 0; i < NN; ++i) {
        float s = b;
        for (int c = 0; c < nchunk; ++c)
            s += part[(size_t)(c * NN + i) * N + n];
        out[(size_t)i * N + n] = s;
    }
}

// ---------- classifier partial: part[chunk][512] = flat[chunk] @ Wc1[chunk,512] ----------
__global__ __launch_bounds__(256) void cls_partial(const float* __restrict__ flat,
                                                   const float* __restrict__ Wc1,
                                                   float* __restrict__ part,
                                                   int BK) {
    const int n = blockIdx.x * 256 + threadIdx.x;  // 0..511
    const int k0 = blockIdx.y * BK;
    float a0 = 0.f, a1 = 0.f, a2 = 0.f, a3 = 0.f;
#pragma unroll 4
    for (int k = 0; k < BK; k += 4) {
        a0 = fmaf(flat[k0 + k + 0], Wc1[(size_t)(k0 + k + 0) * LAT + n], a0);
        a1 = fmaf(flat[k0 + k + 1], Wc1[(size_t)(k0 + k + 1) * LAT + n], a1);
        a2 = fmaf(flat[k0 + k + 2], Wc1[(size_t)(k0 + k + 2) * LAT + n], a2);
        a3 = fmaf(flat[k0 + k + 3], Wc1[(size_t)(k0 + k + 3) * LAT + n], a3);
    }
    part[(size_t)blockIdx.y * LAT + n] = (a0 + a1) + (a2 + a3);
}

// ---------- classifier finish: c = reduce + bc1; pred = sigmoid(c . Wc2 + bc2) ----------
__global__ __launch_bounds__(512) void cls_final(const float* __restrict__ part,
                                                 const float* __restrict__ bc1,
                                                 const float* __restrict__ Wc2,
                                                 const float* __restrict__ bc2,
                                                 float* __restrict__ out,
                                                 int nchunk) {
    __shared__ float red[512];
    const int t = threadIdx.x;
    float s = bc1[t];
    for (int c = 0; c < nchunk; ++c) s += part[(size_t)c * LAT + t];
    red[t] = s * Wc2[t];
    __syncthreads();
    for (int off = 256; off > 0; off >>= 1) {
        if (t < off) red[t] += red[t + off];
        __syncthreads();
    }
    if (t == 0) {
        const float x = red[0] + bc2[0];
        out[0] = 1.f / (1.f + expf(-x));
    }
}

extern "C" void kernel_launch(void* const* d_in, const int* in_sizes, int n_in,
                              void* d_out, int out_size, void* d_ws, size_t ws_size,
                              hipStream_t stream) {
    const float* z   = (const float*)d_in[0];
    const int*   ei  = (const int*)d_in[1];
    const float* W1a = (const float*)d_in[2];
    const float* b1a = (const float*)d_in[3];
    const float* W1b = (const float*)d_in[4];
    const float* b1b = (const float*)d_in[5];
    const float* W2a = (const float*)d_in[6];
    const float* b2a = (const float*)d_in[7];
    const float* W2b = (const float*)d_in[8];
    const float* b2b = (const float*)d_in[9];
    const float* Wc1 = (const float*)d_in[10];
    const float* bc1 = (const float*)d_in[11];
    const float* Wc2 = (const float*)d_in[12];
    const float* bc2 = (const float*)d_in[13];
    float* out = (float*)d_out;
    float* ws  = (float*)d_ws;

    // workspace layout (floats)
    float* h0t  = ws + 0;        // 512*32   = 16384
    float* t1t  = ws + 16384;    // 2048*32  = 65536
    float* h1t  = ws + 81920;    // 2048*32  = 65536
    float* h2t  = ws + 147456;   // 2048*32  = 65536
    float* t2t  = ws + 212992;   // 4096*32  = 131072
    float* part = ws + 344064;   // up to 16*19*4096 = 1245184  (~6.4 MB total)

    // GIN layer 1
    agg1_kernel<<<1, 512, 0, stream>>>(z, ei, h0t);
    gemm19_partial<<<dim3(HID / 256, 8), 256, 0, stream>>>(h0t, W1a, part, HID, 64);    // K=512
    gemm19_reduce_relu_t<<<HID / 256, 256, 0, stream>>>(part, b1a, t1t, HID, 8);
    gemm19_partial<<<dim3(HID / 256, 16), 256, 0, stream>>>(t1t, W1b, part, HID, 128);  // K=2048
    gemm19_reduce_relu_t<<<HID / 256, 256, 0, stream>>>(part, b1b, h1t, HID, 16);

    // GIN layer 2
    agg2_kernel<<<HID / 256, 256, 0, stream>>>(h1t, ei, h2t);
    gemm19_partial<<<dim3(NT / 256, 16), 256, 0, stream>>>(h2t, W2a, part, NT, 128);    // K=2048
    gemm19_reduce_relu_t<<<NT / 256, 256, 0, stream>>>(part, b2a, t2t, NT, 16);
    gemm19_partial<<<dim3(NT / 256, 16), 256, 0, stream>>>(t2t, W2b, part, NT, 256);    // K=4096
    gemm19_reduce_out<<<NT / 256, 256, 0, stream>>>(part, b2b, out + 1, NT, 16);

    // classifier: flat [77824] @ Wc1 [77824,512] ; 77824 = 608*128
    cls_partial<<<dim3(2, 128), 256, 0, stream>>>(out + 1, Wc1, part, 608);
    cls_final<<<1, 512, 0, stream>>>(part, bc1, Wc2, bc2, out, 128);
}